// Round 5
// baseline (339.535 us; speedup 1.0000x reference)
//
#include <hip/hip_runtime.h>
#include <hip/hip_bf16.h>
#include <hip/hip_fp16.h>
#include <stdint.h>

// C[8192,4096] = x[8192,2049] @ filters_real[4096,2049]^T  (fp32 out)
// filters_imag provably dead: Re(x*(a+bi)) = x*a for real x.
// fp16 single GEMM (fp32 acc): err std 4.5e-4 << reference's own 2.5e-3 noise
// (verified R4: absmax 0.015625 == reference-noise prediction).
//
// 256x256x64 8-phase schedule, R5: fragment prefetch one phase ahead
// (af_lo/af_hi split), vmcnt(6) mid-tile drain, sched_barrier(0) phase pins.
// T2 swizzle verified R4: SQ_LDS_BANK_CONFLICT == 0.

#define KIN   2049
#define KPAD  2112            // 33 * 64
#define MDIM  8192
#define NDIM  4096
#define BM    256
#define BN    256
#define BK    64
#define NT    (KPAD / BK)     // 33

typedef _Float16 f16x8 __attribute__((ext_vector_type(8)));
typedef float    f32x4 __attribute__((ext_vector_type(4)));

// ---------------- prep: fp32 -> fp16, zero-padded to KPAD -------------------
// lane t handles 8 consecutive cols -> one 16B store; loads are stride-32B
// scalar dwords (L1 absorbs the 4x line re-touch; stores fully coalesced).
__global__ __launch_bounds__(256) void cvt_f16(const float* __restrict__ xsrc,
                                               const float* __restrict__ fsrc,
                                               _Float16* __restrict__ xa,
                                               _Float16* __restrict__ fb) {
  int r = blockIdx.x;
  const float* src;
  _Float16* dst;
  if (r < MDIM) { src = xsrc + (size_t)r * KIN;          dst = xa + (size_t)r * KPAD; }
  else          { src = fsrc + (size_t)(r - MDIM) * KIN; dst = fb + (size_t)(r - MDIM) * KPAD; }
  int t = threadIdx.x;
  int c0 = t * 8;                      // 0..2047
  float v[8];
#pragma unroll
  for (int u = 0; u < 8; ++u) v[u] = src[c0 + u];
  f16x8 o;
#pragma unroll
  for (int u = 0; u < 8; ++u) o[u] = (_Float16)v[u];
  *reinterpret_cast<f16x8*>(&dst[c0]) = o;   // row base 4224B: 16B-aligned
  if (t < 8) {                         // cols 2048..2111
    f16x8 z = {};
    if (t == 0) z[0] = (_Float16)src[2048];
    *reinterpret_cast<f16x8*>(&dst[2048 + t * 8]) = z;
  }
}

// ---------------- 256^2 8-phase GEMM ----------------------------------------
#define GLDS(SRC, DSTOFF)                                                      \
  __builtin_amdgcn_global_load_lds(                                            \
      (const __attribute__((address_space(1))) void*)(SRC),                    \
      (__attribute__((address_space(3))) void*)(lds + (DSTOFF)), 16, 0, 0)

#define STAGE_A(BUF, HALF, KC) do {                                            \
  GLDS(Asrc0 + (size_t)(HALF) * 128 * KPAD + (KC), (BUF)*65536 + (HALF)*16384 + dst0); \
  GLDS(Asrc1 + (size_t)(HALF) * 128 * KPAD + (KC), (BUF)*65536 + (HALF)*16384 + dst1); \
} while (0)
#define STAGE_B(BUF, HALF, KC) do {                                            \
  GLDS(Bsrc0 + (size_t)(HALF) * 128 * KPAD + (KC), (BUF)*65536 + 32768 + (HALF)*16384 + dst0); \
  GLDS(Bsrc1 + (size_t)(HALF) * 128 * KPAD + (KC), (BUF)*65536 + 32768 + (HALF)*16384 + dst1); \
} while (0)

#define LDA(BUF, QR, DST) do {                                                 \
  int rb_ = (wr * 128 + (QR) * 64 + lr) * 128 + (BUF) * 65536;                 \
  _Pragma("unroll") for (int i = 0; i < 4; ++i) {                              \
    DST[i][0] = *(const f16x8*)(lds + rb_ + i * 2048 + c0);                    \
    DST[i][1] = *(const f16x8*)(lds + rb_ + i * 2048 + c1);                    \
  } } while (0)
#define LDB(BUF, QC, DST) do {                                                 \
  int rb_ = (wc * 64 + (QC) * 32 + lr) * 128 + (BUF) * 65536 + 32768;          \
  _Pragma("unroll") for (int j = 0; j < 2; ++j) {                              \
    DST[j][0] = *(const f16x8*)(lds + rb_ + j * 2048 + c0);                    \
    DST[j][1] = *(const f16x8*)(lds + rb_ + j * 2048 + c1);                    \
  } } while (0)

#define MM(QR, QC, AF, BF) do {                                                \
  __builtin_amdgcn_s_setprio(1);                                               \
  _Pragma("unroll") for (int s = 0; s < 2; ++s)                                \
  _Pragma("unroll") for (int i = 0; i < 4; ++i)                                \
  _Pragma("unroll") for (int j = 0; j < 2; ++j)                                \
    acc[(QR)*4 + i][(QC)*2 + j] = __builtin_amdgcn_mfma_f32_16x16x32_f16(      \
        AF[i][s], BF[j][s], acc[(QR)*4 + i][(QC)*2 + j], 0, 0, 0);             \
  __builtin_amdgcn_s_setprio(0);                                               \
} while (0)

#define BAR() __builtin_amdgcn_s_barrier()
#define SB0() __builtin_amdgcn_sched_barrier(0)

__global__ __launch_bounds__(512, 2) void gemm8_f16(
    const _Float16* __restrict__ A, const _Float16* __restrict__ B,
    float* __restrict__ C) {
  extern __shared__ char lds[];   // 131072 B: [buf][A|B][256][64] f16

  // T1: XCD-bijective swizzle; 512 blocks = 8 XCDs x 64
  int wg  = blockIdx.x;
  int swz = (wg & 7) * 64 + (wg >> 3);
  int brow = (swz >> 4) * BM;     // 32 m-tiles
  int bcol = (swz & 15) * BN;     // 16 n-tiles

  int tid  = threadIdx.x;
  int lane = tid & 63;
  int wid  = tid >> 6;
  int wr = wid >> 2, wc = wid & 3;     // 2x4 wave grid; wave tile 128x64
  int lr = lane & 15, lk = lane >> 4;

  // T2 swizzle (read side): byte ^= ((row&7)<<4)
  int sx = (lr & 7) << 4;
  int c0 = (lk * 16) ^ sx;
  int c1 = (64 + lk * 16) ^ sx;

  // staging: load l covers elems (l*512+tid)*8 of a 128x64 half-tile
  int d0e = tid * 8,         ri0 = d0e >> 6, cb0 = (d0e & 63) * 2;
  int d1e = (512 + tid) * 8, ri1 = d1e >> 6, cb1 = (d1e & 63) * 2;
  int sc0 = cb0 ^ ((ri0 & 7) << 4);    // inverse-swizzled source col (bytes)
  int sc1 = cb1 ^ ((ri1 & 7) << 4);
  const _Float16* Asrc0 = A + (size_t)(brow + ri0) * KPAD + sc0 / 2;
  const _Float16* Asrc1 = A + (size_t)(brow + ri1) * KPAD + sc1 / 2;
  const _Float16* Bsrc0 = B + (size_t)(bcol + ri0) * KPAD + sc0 / 2;
  const _Float16* Bsrc1 = B + (size_t)(bcol + ri1) * KPAD + sc1 / 2;
  int dst0 = tid * 16;            // linear LDS dest (bytes), wave-contiguous
  int dst1 = 8192 + tid * 16;

  f32x4 acc[8][4] = {};
  f16x8 af_lo[4][2], af_hi[4][2], b0[2][2], b1[2][2];

  // prologue: stage A0(0),B0(0),A1(0),B1(0),B0(1),A0(1); drain first 4 halves;
  // pre-read tile0's af_lo/b0 (consumed at ph0).
  STAGE_A(0, 0, 0); STAGE_B(0, 0, 0); STAGE_A(0, 1, 0); STAGE_B(0, 1, 0);
  STAGE_B(1, 0, BK); STAGE_A(1, 0, BK);
  asm volatile("s_waitcnt vmcnt(4)" ::: "memory");
  BAR();
  LDA(0, 0, af_lo); LDB(0, 0, b0);
  SB0();

  for (int kt = 0; kt < NT; ++kt) {
    const int buf = kt & 1, obuf = buf ^ 1;
    // ---- ph0: read b1(kt); stage A1(kt+1); MM(A0,B0)
    LDB(buf, 1, b1);
    if (kt + 1 < NT) STAGE_A(obuf, 1, (size_t)(kt + 1) * BK);
    SB0(); BAR(); SB0();
    MM(0, 0, af_lo, b0);
    SB0(); BAR(); SB0();
    // ---- ph1: read af_hi(kt); stage B1(kt+1); MM(A0,B1)
    LDA(buf, 1, af_hi);
    if (kt + 1 < NT) STAGE_B(obuf, 1, (size_t)(kt + 1) * BK);
    SB0(); BAR(); SB0();
    MM(0, 1, af_lo, b1);
    SB0(); BAR(); SB0();
    // ---- ph2: stage B0(kt+2); MM(A1,B0); drain next tile's A0/B0
    if (kt + 2 < NT) STAGE_B(buf, 0, (size_t)(kt + 2) * BK);
    SB0(); BAR(); SB0();
    MM(1, 0, af_hi, b0);
    if (kt < NT - 2) asm volatile("s_waitcnt vmcnt(6)" ::: "memory");
    else             asm volatile("s_waitcnt vmcnt(0)" ::: "memory");
    SB0(); BAR(); SB0();
    // ---- ph3: read next tile's af_lo/b0; stage A0(kt+2); MM(A1,B1)
    if (kt + 1 < NT) { LDA(obuf, 0, af_lo); LDB(obuf, 0, b0); }
    if (kt + 2 < NT) STAGE_A(buf, 0, (size_t)(kt + 2) * BK);
    SB0(); BAR(); SB0();
    MM(1, 1, af_hi, b1);
    if (kt < NT - 2) asm volatile("s_waitcnt vmcnt(4)" ::: "memory");
    else             asm volatile("s_waitcnt vmcnt(0)" ::: "memory");
    SB0(); BAR(); SB0();
  }

  // epilogue: C/D layout col = lane&15, row = (lane>>4)*4 + reg [m89-verified]
#pragma unroll
  for (int i = 0; i < 8; ++i) {
    int r0 = brow + wr * 128 + i * 16 + lk * 4;
#pragma unroll
    for (int j = 0; j < 4; ++j) {
      int col = bcol + wc * 64 + j * 16 + lr;
#pragma unroll
      for (int r = 0; r < 4; ++r)
        C[(size_t)(r0 + r) * NDIM + col] = acc[i][j][r];
    }
  }
}

// ---------------- fallback (ws too small): naive fp32 -----------------------
__global__ void fallback_fp32(const float* __restrict__ x,
                              const float* __restrict__ f,
                              float* __restrict__ out) {
  __shared__ float xs[KIN + 3];
  int b = blockIdx.y;
  for (int k = threadIdx.x; k < KIN; k += 256) xs[k] = x[(size_t)b * KIN + k];
  __syncthreads();
  int o = blockIdx.x * 256 + threadIdx.x;
  const float* fr = f + (size_t)o * KIN;
  float s = 0.f;
  for (int k = 0; k < KIN; ++k) s += xs[k] * fr[k];
  out[(size_t)b * NDIM + o] = s;
}

// ---------------- launch ----------------------------------------------------
extern "C" void kernel_launch(void* const* d_in, const int* in_sizes, int n_in,
                              void* d_out, int out_size, void* d_ws, size_t ws_size,
                              hipStream_t stream) {
  const float* x  = (const float*)d_in[0];
  const float* fr = (const float*)d_in[1];
  float* out = (float*)d_out;

  const size_t elemsA = (size_t)MDIM * KPAD;
  const size_t elemsB = (size_t)NDIM * KPAD;
  const size_t need   = (elemsA + elemsB) * sizeof(_Float16);

  if (ws_size < need) {
    fallback_fp32<<<dim3(NDIM / 256, MDIM), dim3(256), 0, stream>>>(x, fr, out);
    return;
  }

  _Float16* Ah = (_Float16*)d_ws;
  _Float16* Bh = Ah + elemsA;

  static bool attr_set = false;   // host-side only; same work every call
  if (!attr_set) {
    hipFuncSetAttribute((const void*)gemm8_f16,
                        hipFuncAttributeMaxDynamicSharedMemorySize, 131072);
    attr_set = true;
  }

  cvt_f16<<<dim3(MDIM + NDIM), dim3(256), 0, stream>>>(x, fr, Ah, Bh);
  gemm8_f16<<<dim3((MDIM / BM) * (NDIM / BN)), dim3(512), 131072, stream>>>(Ah, Bh, out);
}